// Round 6
// baseline (2288.692 us; speedup 1.0000x reference)
//
#include <hip/hip_runtime.h>
#include <math.h>

#define NB 4
#define NW 24
#define H 512
#define H2 1024
#define H5 2560
#define NCELL 300   // n*(n+1)/2 valid cells per batch
#define NEED_BYTES ((size_t)72<<20)
#define PGRID 512
#define PTPB 256

// Private fallback workspace: allocated ONCE at library load (outside
// kernel_launch, so graph capture never sees the hipMalloc).
static float* g_buf = nullptr;
__attribute__((constructor)) static void dio_alloc_ws(){
  (void)hipMalloc((void**)&g_buf, NEED_BYTES);
}

typedef __attribute__((ext_vector_type(8))) short bf16x8;   // 8 bf16 (4 VGPRs)
typedef __attribute__((ext_vector_type(4))) float f32x4;
typedef unsigned short ushort_t;

__device__ __forceinline__ int coff(int l){ return l*NW - (l*(l-1))/2; }
__device__ __forceinline__ float sigm(float x){ return 1.f/(1.f+__expf(-x)); }
__device__ __forceinline__ float ftanh(float x){ return 1.f - 2.f/(__expf(2.f*x)+1.f); }

__device__ __forceinline__ ushort_t f2b(float x){  // fp32 -> bf16 RNE
  unsigned int u = __float_as_uint(x);
  u += 0x7FFF + ((u>>16)&1);
  return (ushort_t)(u>>16);
}
__device__ __forceinline__ float b2f(ushort_t h){
  return __uint_as_float(((unsigned int)h)<<16);
}
__device__ __forceinline__ void split_store(ushort_t* __restrict__ ph,
                                            ushort_t* __restrict__ pl,
                                            size_t idx, float x){
  ushort_t h = f2b(x);
  ph[idx] = h;
  pl[idx] = f2b(x - b2f(h));
}

// ---- MALL-scope primitives (proven bit-exact in rounds 3-5):
// producers: atomic stores (write-through) + vmcnt drain + counter RMW;
// consumers: counter spin (atomic load) + PLAIN cached loads of write-once lines.
__device__ __forceinline__ unsigned ldA(const unsigned* p){
  return __hip_atomic_load(p, __ATOMIC_RELAXED, __HIP_MEMORY_SCOPE_AGENT);
}
__device__ __forceinline__ unsigned addA(unsigned* p, unsigned v){
  return __hip_atomic_fetch_add(p, v, __ATOMIC_RELAXED, __HIP_MEMORY_SCOPE_AGENT);
}
__device__ __forceinline__ void stA(float* p, float v){
  __hip_atomic_store((unsigned*)p, __float_as_uint(v),
                     __ATOMIC_RELAXED, __HIP_MEMORY_SCOPE_AGENT);
}
__device__ __forceinline__ void stAu(unsigned* p, unsigned v){
  __hip_atomic_store(p, v, __ATOMIC_RELAXED, __HIP_MEMORY_SCOPE_AGENT);
}
__device__ __forceinline__ void spin_ge(const unsigned* p, unsigned target){
  while (ldA(p) < target) __builtin_amdgcn_s_sleep(8);
}

// full-wave dot: U[lc].[H(rc);C(rc)] (plain cached loads; S added by caller)
__device__ __forceinline__ float compat_dot2(const float* __restrict__ cU,
                                             const float* __restrict__ cH,
                                             const float* __restrict__ cC,
                                             int lc, int rc, int lane){
  const float4* U4  = (const float4*)(cU + (size_t)lc*H2);
  const float4* Hr4 = (const float4*)(cH + (size_t)rc*H);
  const float4* Cr4 = (const float4*)(cC + (size_t)rc*H);
  float p = 0.f;
  #pragma unroll
  for (int it=0; it<2; it++){
    float4 u = U4[lane + 64*it], h = Hr4[lane + 64*it];
    p += u.x*h.x + u.y*h.y + u.z*h.z + u.w*h.w;
  }
  #pragma unroll
  for (int it=0; it<2; it++){
    float4 u = U4[128 + lane + 64*it], c = Cr4[lane + 64*it];
    p += u.x*c.x + u.y*c.y + u.z*c.z + u.w*c.w;
  }
  #pragma unroll
  for (int off=32; off>0; off>>=1) p += __shfl_down(p, off);
  return p;
}

// ---- merged init: split Wi/Ws, transpose+split Wbil, leaves, counter zero
__global__ void k_init(const float* __restrict__ seqt,
                       const float* __restrict__ Wi, const float* __restrict__ Ws,
                       const float* __restrict__ Wbil,
                       ushort_t* __restrict__ WiBh, ushort_t* __restrict__ WiBl,
                       ushort_t* __restrict__ WsBh, ushort_t* __restrict__ WsBl,
                       ushort_t* __restrict__ WbilTh, ushort_t* __restrict__ WbilTl,
                       float* __restrict__ cH, float* __restrict__ cC,
                       float* __restrict__ cS2,
                       ushort_t* __restrict__ cHbh, ushort_t* __restrict__ cHbl,
                       ushort_t* __restrict__ cCbh, ushort_t* __restrict__ cCbl,
                       unsigned* __restrict__ ctr){
  const int blk = blockIdx.x, t = threadIdx.x;
  if (blk < 10240){                       // Wi/Ws split (2*H5*H elems exactly)
    int i = blk*256 + t;
    const int n = H5*H;
    if (i < n) split_store(WiBh, WiBl, i, Wi[i]);
    else       split_store(WsBh, WsBl, i-n, Ws[i-n]);
  } else if (blk < 11264){                // Wbil transpose+split (1024 tiles)
    __shared__ float tile[32][33];
    int tb = blk - 10240;
    int tr = (tb>>5)*32, tc = (tb&31)*32;
    int tx = t & 31, ty = t >> 5;         // 32 x 8
    #pragma unroll
    for (int i=0;i<32;i+=8)
      tile[ty+i][tx] = Wbil[(size_t)(tr+ty+i)*H2 + tc+tx];
    __syncthreads();
    #pragma unroll
    for (int i=0;i<32;i+=8)
      split_store(WbilTh, WbilTl, (size_t)(tc+ty+i)*H2 + tr+tx, tile[tx][ty+i]);
  } else if (blk < 11456){                // leaves (192 blocks)
    int tid = (blk-11264)*256 + t;
    if (tid < NB*NW*H){
      int b = tid/(NW*H); int r = tid%(NW*H); int i = r/H; int d = r%H;
      size_t idx = (size_t)(b*NCELL + i)*H + d;     // coff(0)==0
      float hv = seqt[(size_t)(b*NW+i)*H2 + d];
      float cv = seqt[(size_t)(b*NW+i)*H2 + H + d];
      cH[idx]=hv; cC[idx]=cv;
      split_store(cHbh,cHbl,idx,hv);
      split_store(cCbh,cCbl,idx,cv);
      if (d==0) cS2[(b*NW + 0)*32 + i] = 0.f;   // leaf scores (padded cS)
    }
  } else {                                // per-stage work counters
    for (int i=t; i<NW*192; i+=256) ctr[i] = 0u;
  }
}

__device__ __forceinline__ void mfma3(f32x4& acc, bf16x8 ah, bf16x8 al,
                                      bf16x8 bh, bf16x8 bl){
  // split product; lo*lo (~2^-34 rel) dropped
  acc = __builtin_amdgcn_mfma_f32_16x16x32_bf16(ah, bh, acc, 0,0,0);
  acc = __builtin_amdgcn_mfma_f32_16x16x32_bf16(ah, bl, acc, 0,0,0);
  acc = __builtin_amdgcn_mfma_f32_16x16x32_bf16(al, bh, acc, 0,0,0);
}

// ---- one proj j-tile (per wave): M=Pd rows of batch b, direct-global B-frags.
// Same chain order + ((0+1)+(2+3))+((4+5)+(6+7)) tree as round 2 -> bit-exact.
__device__ __forceinline__ void proj_tile(
    int b, int jt, int L, int Pd,
    const ushort_t* __restrict__ WiBh, const ushort_t* __restrict__ WiBl,
    const ushort_t* __restrict__ WsBh, const ushort_t* __restrict__ WsBl,
    const ushort_t* __restrict__ WbilTh, const ushort_t* __restrict__ WbilTl,
    const float* __restrict__ bi, const float* __restrict__ bs,
    const ushort_t* __restrict__ cHbh, const ushort_t* __restrict__ cHbl,
    const ushort_t* __restrict__ cCbh, const ushort_t* __restrict__ cCbl,
    float* cPI, float* cPS, float* cU, int lane)
{
  const int r = lane & 15, q = lane >> 4;
  int kind, j0;
  if (jt < 160){ kind=0; j0 = jt*16; }
  else if (jt < 320){ kind=1; j0 = (jt-160)*16; }
  else { kind=2; j0 = (jt-320)*16; }
  const int jo = j0 + r;
  float bias = 0.f;
  if (kind==0) bias = bi[jo] + ((jo>=H && jo<3*H)?1.f:0.f);   // ins_bias [H,3H)
  else if (kind==1) bias = bs[jo];
  const f32x4 z4 = {0.f,0.f,0.f,0.f};

  for (int m0 = 0; m0 < Pd; m0 += 16){
    const int nm = (Pd - m0 < 16) ? (Pd - m0) : 16;
    const int mg = m0 + (r < nm ? r : 0);
    const size_t arow = (size_t)(b*NCELL + coff(L) + mg)*H;
    f32x4 acc[8];
    #pragma unroll
    for (int w=0;w<8;w++) acc[w] = z4;
    if (kind < 2){
      const ushort_t* bh_ = (kind==0 ? WiBh : WsBh) + (size_t)jo*H;
      const ushort_t* bl_ = (kind==0 ? WiBl : WsBl) + (size_t)jo*H;
      #pragma unroll
      for (int w=0; w<8; w++){
        #pragma unroll
        for (int s=0;s<2;s++){
          const int ko = w*64 + q*8 + s*32;
          bf16x8 ah = *(const bf16x8*)(cHbh + arow + ko);
          bf16x8 al = *(const bf16x8*)(cHbl + arow + ko);
          bf16x8 bh = *(const bf16x8*)(bh_ + ko);
          bf16x8 bl = *(const bf16x8*)(bl_ + ko);
          mfma3(acc[w], ah, al, bh, bl);
        }
      }
    } else {
      const ushort_t* bh_ = WbilTh + (size_t)jo*H2;
      const ushort_t* bl_ = WbilTl + (size_t)jo*H2;
      #pragma unroll
      for (int w=0; w<8; w++){
        const ushort_t* ah_ = (w<4 ? cHbh : cCbh) + arow;
        const ushort_t* al_ = (w<4 ? cHbl : cCbl) + arow;
        const int kg0 = w*128, ka0 = kg0 & 511;
        #pragma unroll
        for (int s=0;s<4;s++){
          const int so = s*32 + q*8;
          bf16x8 ah = *(const bf16x8*)(ah_ + ka0 + so);
          bf16x8 al = *(const bf16x8*)(al_ + ka0 + so);
          bf16x8 bh = *(const bf16x8*)(bh_ + kg0 + so);
          bf16x8 bl = *(const bf16x8*)(bl_ + kg0 + so);
          mfma3(acc[w], ah, al, bh, bl);
        }
      }
    }
    f32x4 tot = ((acc[0]+acc[1])+(acc[2]+acc[3])) + ((acc[4]+acc[5])+(acc[6]+acc[7]));
    #pragma unroll
    for (int reg=0; reg<4; reg++){
      const int m = q*4 + reg;
      if (m < nm){
        const size_t cellj = (size_t)(b*NCELL + coff(L) + m0 + m);
        const float v = tot[reg];
        if (kind==0)      stA(&cPI[cellj*H5 + jo], v + bias);
        else if (kind==1) stA(&cPS[cellj*H5 + jo], v + bias);
        else              stA(&cU [cellj*H2 + jo], v);
      }
    }
  }
}

// ---- the whole inside pass as ONE persistent work-stealing kernel.
// Counters per stage L at ctr + L*192 (each counter on its own 128B):
//   [0]=grabA [32]=doneA (combine items, NB*Pd*16)
//   [64]=grabB [96]=doneB (proj groups of 4 tiles, NB*96)
//   [128]=grabW [160]=doneW (compat writer items for diag L+1)
__global__ void __launch_bounds__(PTPB)
k_pipe(const ushort_t* __restrict__ WiBh, const ushort_t* __restrict__ WiBl,
       const ushort_t* __restrict__ WsBh, const ushort_t* __restrict__ WsBl,
       const ushort_t* __restrict__ WbilTh, const ushort_t* __restrict__ WbilTl,
       const float* __restrict__ bi, const float* __restrict__ bs,
       ushort_t* __restrict__ cHbh, ushort_t* __restrict__ cHbl,
       ushort_t* __restrict__ cCbh, ushort_t* __restrict__ cCbl,
       float* cPI, float* cPS, float* cU,
       float* cH, float* cC, float* cS2, float* cmpT,
       unsigned* ctr, float* __restrict__ out)
{
  __shared__ float compat_s[32];
  __shared__ float wts_s[32];
  __shared__ float S_s;
  __shared__ float partH[8][32];
  __shared__ float partC[8][32];
  __shared__ int shi;

  const int t = threadIdx.x, lane = t & 63, wave = t >> 6;

  for (int L = 0; L < NW; L++){
    const int Pd = NW - L;
    unsigned* C = ctr + L*192;

    if (L >= 1){
      // ---- stage-entry gate: proj(L-1) done; writers(L-1) done (interior)
      unsigned* Cp = ctr + (L-1)*192;
      spin_ge(Cp + 96, (unsigned)(NB*96));
      if (L >= 3) spin_ge(Cp + 160, (unsigned)(NB*Pd*(L-2)));

      // ---- phase A1: combine items (cell, 32-dim group); chunks of 4
      const int nA = NB*Pd*16;
      for(;;){
        __syncthreads();
        if (t == 0){
          unsigned cur = ldA(C + 0);
          shi = (cur < (unsigned)nA) ? (int)addA(C + 0, 4u) : nA;
        }
        __syncthreads();
        const int v0 = shi;
        if (v0 >= nA) break;
        const int ne = (nA - v0 < 4) ? (nA - v0) : 4;
        for (int i = 0; i < ne; i++){
          const int it = v0 + i;
          const int dg = it & 15, cell = it >> 4;
          const int b = cell / Pd, left = cell % Pd;
          // phase 1: boundary compat inline; interior from write-once buffer
          if (wave == 0){
            int lc = b*NCELL + left;                       // (left,0) leaf
            int rc = b*NCELL + coff(L-1) + left+1;
            float v = compat_dot2(cU, cH, cC, lc, rc, lane)
                    + cS2[(b*NW + 0)*32 + left] + cS2[(b*NW + L-1)*32 + left+1];
            if (lane==0) compat_s[0] = v;
          } else if (wave == 1 && L >= 2){
            int lc = b*NCELL + coff(L-1) + left;
            int rc = b*NCELL + left+L;                     // (left+L,0) leaf
            float v = compat_dot2(cU, cH, cC, lc, rc, lane)
                    + cS2[(b*NW + L-1)*32 + left] + cS2[(b*NW + 0)*32 + left+L];
            if (lane==0) compat_s[L-1] = v;
          }
          if (t >= 1 && t <= L-2)
            compat_s[t] = cmpT[((size_t)L*NB*NW + b*NW + left)*(size_t)NW + t];
          __syncthreads();
          // phase 2: softmax (serial on t0, order-identical to round 2)
          if (t == 0){
            float mx = -1e30f;
            for (int k=0;k<L;k++) mx = fmaxf(mx, compat_s[k]);
            float den = 0.f;
            for (int k=0;k<L;k++){ float e = __expf(compat_s[k]-mx); wts_s[k]=e; den+=e; }
            float inv = 1.f/den, S = 0.f;
            for (int k=0;k<L;k++){ wts_s[k]*=inv; S += wts_s[k]*compat_s[k]; }
            S_s = S;
          }
          __syncthreads();
          // phase 3: dims dg*32+dloc, 8-way kpar split (bit-exact vs round 2)
          const int dloc = t & 31;
          const int dim = dg*32 + dloc;
          const int kpar = t >> 5;
          float aH = 0.f, aC = 0.f;
          for (int k=kpar; k<L; k+=8){
            float wk = wts_s[k];
            int lc = b*NCELL + coff(k) + left;
            int rc = b*NCELL + coff(L-1-k) + left+k+1;
            const float* PI = cPI + (size_t)lc*H5;
            const float* PS = cPS + (size_t)rc*H5;
            float p0 = PI[dim]     + PS[dim];
            float p1 = PI[H+dim]   + PS[H+dim];
            float p2 = PI[2*H+dim] + PS[2*H+dim];
            float p3 = PI[3*H+dim] + PS[3*H+dim];
            float p4 = PI[4*H+dim] + PS[4*H+dim];
            float lcv = cC[(size_t)lc*H + dim];
            float rcv = cC[(size_t)rc*H + dim];
            float mem = sigm(p1)*lcv + sigm(p2)*rcv + sigm(p0)*ftanh(p3);
            float h = sigm(p4)*ftanh(mem);
            aH += wk*h; aC += wk*mem;
          }
          if (kpar > 0){ partH[kpar][dloc]=aH; partC[kpar][dloc]=aC; }
          __syncthreads();
          if (kpar == 0){
            #pragma unroll
            for (int qq=1;qq<8;qq++){ aH += partH[qq][dloc]; aC += partC[qq][dloc]; }
            if (L == NW-1){                      // root: write output
              out[b*H2 + dim]     = aH;
              out[b*H2 + H + dim] = aC;
            } else {
              const size_t nc = (size_t)(b*NCELL + coff(L) + left);
              stA(&cH[nc*H + dim], aH);
              stA(&cC[nc*H + dim], aC);
              ushort_t hH = f2b(aH), lH = f2b(aH - b2f(hH));
              ushort_t hC = f2b(aC), lC = f2b(aC - b2f(hC));
              unsigned nh = (unsigned)__shfl_down((int)hH, 1);
              unsigned nl = (unsigned)__shfl_down((int)lH, 1);
              unsigned mh = (unsigned)__shfl_down((int)hC, 1);
              unsigned ml = (unsigned)__shfl_down((int)lC, 1);
              if (!(t & 1)){
                const size_t pi = (nc*H + dim) >> 1;
                stAu((unsigned*)cHbh + pi, (unsigned)hH | (nh<<16));
                stAu((unsigned*)cHbl + pi, (unsigned)lH | (nl<<16));
                stAu((unsigned*)cCbh + pi, (unsigned)hC | (mh<<16));
                stAu((unsigned*)cCbl + pi, (unsigned)lC | (ml<<16));
              }
              if (t == 0 && dg == 0) stA(&cS2[(b*NW + L)*32 + left], S_s);
            }
          }
          __syncthreads();   // LDS reuse for next item
        }
        __syncthreads();     // drain all waves' stores (vmcnt before barrier)
        if (t == 0) addA(C + 32, (unsigned)ne);
      }

      // ---- phase A2: compat writers for diag L+1 (read diag <= L-1 only)
      const int nWt = (L <= NW-2 && L >= 2) ? NB*(Pd-1)*(L-1) : 0;
      if (nWt > 0) for(;;){
        __syncthreads();
        if (t == 0){
          unsigned cur = ldA(C + 128);
          shi = (cur < (unsigned)nWt) ? (int)addA(C + 128, 4u) : nWt;
        }
        __syncthreads();
        const int w0 = shi;
        if (w0 >= nWt) break;
        const int w = w0 + wave;
        if (w < nWt){
          const int per = (Pd-1)*(L-1);
          const int b = w / per, rr = w % per;
          const int left = rr / (L-1);
          const int k = 1 + rr % (L-1);
          int lc = b*NCELL + coff(k) + left;
          int rc = b*NCELL + coff(L-k) + left+k+1;
          float v = compat_dot2(cU, cH, cC, lc, rc, lane)
                  + cS2[(b*NW + k)*32 + left] + cS2[(b*NW + (L-k))*32 + left+k+1];
          if (lane == 0)
            stA(&cmpT[((size_t)(L+1)*NB*NW + b*NW + left)*(size_t)NW + k], v);
        }
        __syncthreads();
        if (t == 0) addA(C + 160, (unsigned)((nWt - w0 < 4) ? (nWt - w0) : 4));
      }

      if (L == NW-1) break;     // no proj after last combine
      // ---- proj gate: all combine items of diag L done
      spin_ge(C + 32, (unsigned)(NB*Pd*16));
    }

    // ---- phase B: proj diag L (groups of 4 j-tiles, one tile per wave)
    const int nB = NB*96;
    for(;;){
      __syncthreads();
      if (t == 0){
        unsigned cur = ldA(C + 64);
        shi = (cur < (unsigned)nB) ? (int)addA(C + 64, 1u) : nB;
      }
      __syncthreads();
      const int g = shi;
      if (g >= nB) break;
      const int b = g / 96, grp = g % 96;
      proj_tile(b, grp*4 + wave, L, Pd,
                WiBh, WiBl, WsBh, WsBl, WbilTh, WbilTl, bi, bs,
                cHbh, cHbl, cCbh, cCbl, cPI, cPS, cU, lane);
      __syncthreads();          // drain all waves' stores
      if (t == 0) addA(C + 96, 1u);
    }
  }
}

extern "C" void kernel_launch(void* const* d_in, const int* in_sizes, int n_in,
                              void* d_out, int out_size, void* d_ws, size_t ws_size,
                              hipStream_t stream){
  const float* seqt = (const float*)d_in[0];
  const float* Wi   = (const float*)d_in[1];
  const float* bi   = (const float*)d_in[2];
  const float* Ws   = (const float*)d_in[3];
  const float* bs   = (const float*)d_in[4];
  const float* Wbil = (const float*)d_in[5];
  float* out = (float*)d_out;

  float* p = (ws_size >= NEED_BYTES && g_buf == nullptr) ? (float*)d_ws : g_buf;
  float* cH   = p; p += (size_t)NB*NCELL*H;
  float* cC   = p; p += (size_t)NB*NCELL*H;
  float* cPI  = p; p += (size_t)NB*NCELL*H5;
  float* cPS  = p; p += (size_t)NB*NCELL*H5;
  float* cU   = p; p += (size_t)NB*NCELL*H2;
  float* cS2  = p; p += (size_t)NB*NW*32;          // padded: 128B per (b,diag)
  float* cmpT = p; p += (size_t)NW*NB*NW*NW;       // per-stage write-once compat
  ushort_t* u = (ushort_t*)p;
  ushort_t* WiBh   = u; u += (size_t)H5*H;
  ushort_t* WiBl   = u; u += (size_t)H5*H;
  ushort_t* WsBh   = u; u += (size_t)H5*H;
  ushort_t* WsBl   = u; u += (size_t)H5*H;
  ushort_t* WbilTh = u; u += (size_t)H2*H2;
  ushort_t* WbilTl = u; u += (size_t)H2*H2;
  ushort_t* cHbh   = u; u += (size_t)NB*NCELL*H;
  ushort_t* cHbl   = u; u += (size_t)NB*NCELL*H;
  ushort_t* cCbh   = u; u += (size_t)NB*NCELL*H;
  ushort_t* cCbl   = u; u += (size_t)NB*NCELL*H;
  unsigned* ctr    = (unsigned*)u;   // NW*192 u32 (4B-aligned: even ushorts)

  k_init<<<11457, 256, 0, stream>>>(seqt, Wi, Ws, Wbil,
      WiBh, WiBl, WsBh, WsBl, WbilTh, WbilTl,
      cH, cC, cS2, cHbh, cHbl, cCbh, cCbl, ctr);

  k_pipe<<<PGRID, PTPB, 0, stream>>>(
      WiBh, WiBl, WsBh, WsBl, WbilTh, WbilTl, bi, bs,
      cHbh, cHbl, cCbh, cCbl, cPI, cPS, cU, cH, cC, cS2, cmpT, ctr, out);
}

// Round 7
// 577.856 us; speedup vs baseline: 3.9607x; 3.9607x over previous
//
#include <hip/hip_runtime.h>
#include <math.h>

#define NB 4
#define NW 24
#define H 512
#define H2 1024
#define H5 2560
#define NCELL 300   // n*(n+1)/2 valid cells per batch
#define NEED_BYTES ((size_t)72<<20)

// Private fallback workspace: allocated ONCE at library load (outside
// kernel_launch, so graph capture never sees the hipMalloc).
static float* g_buf = nullptr;
__attribute__((constructor)) static void dio_alloc_ws(){
  (void)hipMalloc((void**)&g_buf, NEED_BYTES);
}

typedef __attribute__((ext_vector_type(8))) short bf16x8;   // 8 bf16 (4 VGPRs)
typedef __attribute__((ext_vector_type(4))) float f32x4;
typedef unsigned short ushort_t;

__device__ __forceinline__ int coff(int l){ return l*NW - (l*(l-1))/2; }
__device__ __forceinline__ float sigm(float x){ return 1.f/(1.f+__expf(-x)); }
__device__ __forceinline__ float ftanh(float x){ return 1.f - 2.f/(__expf(2.f*x)+1.f); }

__device__ __forceinline__ ushort_t f2b(float x){  // fp32 -> bf16 RNE
  unsigned int u = __float_as_uint(x);
  u += 0x7FFF + ((u>>16)&1);
  return (ushort_t)(u>>16);
}
__device__ __forceinline__ float b2f(ushort_t h){
  return __uint_as_float(((unsigned int)h)<<16);
}
// split-bf16: x ~= hi + lo with effective ~2^-17 relative error
__device__ __forceinline__ void split_store(ushort_t* __restrict__ ph,
                                            ushort_t* __restrict__ pl,
                                            size_t idx, float x){
  ushort_t h = f2b(x);
  ph[idx] = h;
  pl[idx] = f2b(x - b2f(h));
}

// async global->LDS copy, 16B per lane (dwordx4). LDS dest = uniform base +
// lane*16 (HW rule, learn_hip m104); global src is per-lane.
__device__ __forceinline__ void gload_lds16(const void* g, void* l){
  __builtin_amdgcn_global_load_lds(
      (const __attribute__((address_space(1))) unsigned int*)g,
      (__attribute__((address_space(3))) unsigned int*)l, 16, 0, 0);
}

// full-wave dot: compat(lc,rc) = U[lc].[H(rc);C(rc)] + S[lc] + S[rc]
__device__ __forceinline__ float compat_dot(const float* __restrict__ cU,
                                            const float* __restrict__ cH,
                                            const float* __restrict__ cC,
                                            const float* __restrict__ cS,
                                            int lc, int rc, int lane){
  const float4* U4  = (const float4*)(cU + (size_t)lc*H2);
  const float4* Hr4 = (const float4*)(cH + (size_t)rc*H);
  const float4* Cr4 = (const float4*)(cC + (size_t)rc*H);
  float p = 0.f;
  #pragma unroll
  for (int it=0; it<2; it++){
    float4 u = U4[lane + 64*it], h = Hr4[lane + 64*it];
    p += u.x*h.x + u.y*h.y + u.z*h.z + u.w*h.w;
  }
  #pragma unroll
  for (int it=0; it<2; it++){
    float4 u = U4[128 + lane + 64*it], c = Cr4[lane + 64*it];
    p += u.x*c.x + u.y*c.y + u.z*c.z + u.w*c.w;
  }
  #pragma unroll
  for (int off=32; off>0; off>>=1) p += __shfl_down(p, off);
  return p + cS[lc] + cS[rc];
}

// ---- merged init: weight blobs (pre-swizzled LDS images), leaves.
// WWblob: 320 tiles x 32KB. Tile jt<160 = Wi rows [jt*16,+16); jt in
// [160,320) = Ws. Byte layout inside a tile == proj's LDS image:
//   h at ((row<<10)+(col<<1))^((row&7)<<4), l at +16384.
// WBblob: 64 tiles x 64KB (Wbil columns, transposed):
//   h at ((row<<11)+(k<<1))^((row&7)<<4), l at +32768; row=j%16, k=0..1023.
__global__ void k_init(const float* __restrict__ seqt,
                       const float* __restrict__ Wi, const float* __restrict__ Ws,
                       const float* __restrict__ Wbil,
                       ushort_t* __restrict__ WWblob, ushort_t* __restrict__ WBblob,
                       float* __restrict__ cH, float* __restrict__ cC, float* __restrict__ cS,
                       ushort_t* __restrict__ cHbh, ushort_t* __restrict__ cHbl,
                       ushort_t* __restrict__ cCbh, ushort_t* __restrict__ cCbl){
  const int blk = blockIdx.x, t = threadIdx.x;
  if (blk < 1280){                        // Wi/Ws -> WWblob (8-elem chunks)
    const int gid = blk*256 + t;          // 327680 chunks total
    const int half = 163840;
    const float* mat = (gid < half) ? Wi : Ws;
    const int cid = (gid < half) ? gid : gid - half;
    const int j = cid >> 6;               // row 0..2559
    const int c0 = (cid & 63) << 3;       // col chunk base
    const int tile = ((gid < half) ? 0 : 160) + (j >> 4);
    const int row = j & 15;
    const float4* s = (const float4*)(mat + (size_t)j*H + c0);
    float4 a = s[0], b4 = s[1];
    float xs[8] = {a.x,a.y,a.z,a.w, b4.x,b4.y,b4.z,b4.w};
    union { ushort_t u[8]; bf16x8 v; } hh, ll;
    #pragma unroll
    for (int i=0;i<8;i++){
      ushort_t h = f2b(xs[i]);
      hh.u[i] = h; ll.u[i] = f2b(xs[i] - b2f(h));
    }
    char* base = (char*)WWblob + (size_t)tile*32768;
    const int off = ((row<<10) + (c0<<1)) ^ ((row&7)<<4);
    *(bf16x8*)(base + off) = hh.v;
    *(bf16x8*)(base + 16384 + off) = ll.v;
  } else if (blk < 2304){                 // Wbil transpose -> WBblob (1024 tiles)
    __shared__ float tile[32][33];
    int tb = blk - 1280;
    int tr = (tb>>5)*32, tc = (tb&31)*32;
    int tx = t & 31, ty = t >> 5;         // 32 x 8
    #pragma unroll
    for (int i=0;i<32;i+=8)
      tile[ty+i][tx] = Wbil[(size_t)(tr+ty+i)*H2 + tc+tx];
    __syncthreads();
    if (t < 128){                         // 32 cols x 4 k-chunks of 8
      const int c = t & 31, r0 = (t >> 5) << 3;
      const int jg = tc + c;              // output row (Wbil column)
      const int k0 = tr + r0;             // output k-chunk base
      union { ushort_t u[8]; bf16x8 v; } hh, ll;
      #pragma unroll
      for (int i=0;i<8;i++){
        float x = tile[r0+i][c];
        ushort_t h = f2b(x);
        hh.u[i] = h; ll.u[i] = f2b(x - b2f(h));
      }
      char* base = (char*)WBblob + (size_t)(jg>>4)*65536;
      const int row = jg & 15;
      const int off = ((row<<11) + (k0<<1)) ^ ((row&7)<<4);
      *(bf16x8*)(base + off) = hh.v;
      *(bf16x8*)(base + 32768 + off) = ll.v;
    }
  } else {                                // leaves (192 blocks)
    int tid = (blk-2304)*256 + t;
    if (tid < NB*NW*H){
      int b = tid/(NW*H); int r = tid%(NW*H); int i = r/H; int d = r%H;
      size_t idx = (size_t)(b*NCELL + i)*H + d;     // coff(0)==0
      float hv = seqt[(size_t)(b*NW+i)*H2 + d];
      float cv = seqt[(size_t)(b*NW+i)*H2 + H + d];
      cH[idx]=hv; cC[idx]=cv;
      split_store(cHbh,cHbl,idx,hv);
      split_store(cCbh,cCbl,idx,cv);
      if (d==0) cS[b*NCELL+i] = 0.f;
    }
  }
}

__device__ __forceinline__ void mfma3(f32x4& acc, bf16x8 ah, bf16x8 al,
                                      bf16x8 bh, bf16x8 bl){
  // split product; lo*lo (~2^-34 rel) dropped
  acc = __builtin_amdgcn_mfma_f32_16x16x32_bf16(ah, bh, acc, 0,0,0);
  acc = __builtin_amdgcn_mfma_f32_16x16x32_bf16(ah, bl, acc, 0,0,0);
  acc = __builtin_amdgcn_mfma_f32_16x16x32_bf16(al, bh, acc, 0,0,0);
}

// ---- MFMA projections, one block per j-tile, weights LDS-resident.
// grid.x = 384 (0-159: PI, 160-319: PS, 320-383: U), 512 threads.
// Weight tile staged via global_load_lds width-16 from the pre-swizzled
// blob (linear byte copy -> the exact LDS image the reg-staging produced;
// ds_read side unchanged -> bit-exact). Wave pairs sweep m-tiles: even wave
// = chains 0-3, odd = 4-7; final sA+sB matches the 8-wave tree exactly.
__global__ void __launch_bounds__(512)
k_proj3(const ushort_t* __restrict__ WWblob, const ushort_t* __restrict__ WBblob,
        const float* __restrict__ bi, const float* __restrict__ bs,
        const ushort_t* __restrict__ cHbh, const ushort_t* __restrict__ cHbl,
        const ushort_t* __restrict__ cCbh, const ushort_t* __restrict__ cCbl,
        float* __restrict__ cPI, float* __restrict__ cPS, float* __restrict__ cU,
        int d, int P)
{
  __shared__ __attribute__((aligned(16))) ushort_t wlds[32768];  // 64 KB
  __shared__ f32x4 red[8][64];                                   // 8 KB
  const int t = threadIdx.x, wv = t>>6, lane = t&63;
  const int r = lane & 15;   // A row (m) / B row (j) / D col
  const int q = lane >> 4;   // quad: k = q*8 + i
  const int jt = blockIdx.x;

  int kind, j0;
  if (jt < 160){ kind=0; j0 = jt*16; }
  else if (jt < 320){ kind=1; j0 = (jt-160)*16; }
  else { kind=2; j0 = (jt-320)*16; }

  // ---- stage weights into LDS: linear async copy of the blob image
  {
    const char* blob = (kind < 2)
        ? (const char*)WWblob + (size_t)jt*32768
        : (const char*)WBblob + (size_t)(jt-320)*65536;
    const int nseg = (kind < 2) ? 4 : 8;          // 8KB segments
    for (int i = 0; i < nseg; i++){
      const int lo = i*8192 + wv*1024;
      gload_lds16(blob + lo + lane*16, (char*)wlds + lo);
    }
    asm volatile("s_waitcnt vmcnt(0)" ::: "memory");
  }
  __syncthreads();

  const int Mtot = NB*P, mt = (Mtot+15)>>4;
  const int swz = (r&7)<<4;
  const char* wb = (const char*)wlds;
  const int jo = j0 + r;
  float bias = 0.f;
  if (kind==0) bias = bi[jo] + ((jo>=H && jo<3*H)?1.f:0.f);   // ins_bias on [H,3H)
  else if (kind==1) bias = bs[jo];

  const f32x4 z4 = {0.f,0.f,0.f,0.f};
  const int units = 2*mt;                 // (m-tile, K-half) pairs
  const int rounds = (units + 7) >> 3;
  for (int rd = 0; rd < rounds; rd++){
    const int u = rd*8 + wv;
    const int half = u & 1;               // wv parity (rd*8 even)
    const int mtile = u >> 1;
    f32x4 sA = z4;
    int m0 = 0, nm = 0;
    if (u < units){
      m0 = mtile*16;
      nm = min(16, Mtot - m0);
      const int mg = m0 + (r < nm ? r : 0);
      const size_t arow = (size_t)((mg/P)*NCELL + coff(d) + mg%P)*H;
      f32x4 acc[4];
      #pragma unroll
      for (int wi=0;wi<4;wi++) acc[wi] = z4;
      if (kind < 2){
        #pragma unroll
        for (int wi=0; wi<4; wi++){
          const int w = half*4 + wi;      // chain id 0..7
          #pragma unroll
          for (int s=0;s<2;s++){
            const int ko = w*64 + q*8 + s*32;
            bf16x8 ah = *(const bf16x8*)(cHbh + arow + ko);
            bf16x8 al = *(const bf16x8*)(cHbl + arow + ko);
            const int bo = ((r<<10) + (ko<<1)) ^ swz;
            bf16x8 bh = *(const bf16x8*)(wb + bo);
            bf16x8 bl = *(const bf16x8*)(wb + 16384 + bo);
            mfma3(acc[wi], ah, al, bh, bl);
          }
        }
      } else {
        // U: chains 0-3 -> H chart, 4-7 -> C chart; global k = w*128 + ...
        const ushort_t* ah_ = (half==0 ? cHbh : cCbh) + arow;
        const ushort_t* al_ = (half==0 ? cHbl : cCbl) + arow;
        #pragma unroll
        for (int wi=0; wi<4; wi++){
          const int w = half*4 + wi;
          const int kg0 = w*128, ka0 = kg0 & 511;
          #pragma unroll
          for (int s=0;s<4;s++){
            const int so = s*32 + q*8;
            bf16x8 ah = *(const bf16x8*)(ah_ + ka0 + so);
            bf16x8 al = *(const bf16x8*)(al_ + ka0 + so);
            const int bo = ((r<<11) + ((kg0+so)<<1)) ^ swz;
            bf16x8 bh = *(const bf16x8*)(wb + bo);
            bf16x8 bl = *(const bf16x8*)(wb + 32768 + bo);
            mfma3(acc[wi], ah, al, bh, bl);
          }
        }
      }
      sA = (acc[0]+acc[1]) + (acc[2]+acc[3]);   // half-subtree, fixed order
    }
    red[wv][lane] = sA;
    __syncthreads();
    if (half==0 && u < units){
      f32x4 tot = red[wv][lane] + red[wv|1][lane];   // ((0+1)+(2+3))+((4+5)+(6+7))
      #pragma unroll
      for (int reg=0; reg<4; reg++){
        const int m = q*4 + reg;
        if (m < nm){
          const int mg2 = m0 + m;
          const size_t cell = (size_t)((mg2/P)*NCELL + coff(d) + mg2%P);
          const float v = tot[reg];
          if (kind==0)      cPI[cell*H5 + jo] = v + bias;
          else if (kind==1) cPS[cell*H5 + jo] = v + bias;
          else              cU [cell*H2 + jo] = v;
        }
      }
    }
    __syncthreads();   // red reused next round
  }
}

// ---- combine diagonal L (round-2 structure; root stage writes out directly).
// grid.x = NB*P*16 phase blocks + ceil(NB*(P-1)*(L-1)/4) writer blocks.
__global__ void __launch_bounds__(256)
k_combine3(const float* __restrict__ cPI, const float* __restrict__ cPS,
           const float* __restrict__ cU,
           float* __restrict__ cH, float* __restrict__ cC, float* __restrict__ cS,
           ushort_t* __restrict__ cHbh, ushort_t* __restrict__ cHbl,
           ushort_t* __restrict__ cCbh, ushort_t* __restrict__ cCbl,
           const float* __restrict__ compatR, float* __restrict__ compatW,
           float* __restrict__ out, int L, int P){
  const int t = threadIdx.x;
  const int lane = t & 63;
  const int wave = t >> 6;
  const int nphase = NB*P*16;
  const int blk = blockIdx.x;

  if (blk >= nphase){
    // writer: one wave per (cell of diag L+1, split k in [1,L-1])
    const int P1 = P-1;
    const int nterm = L-1;
    int tid = (blk-nphase)*4 + wave;
    if (P1 > 0 && nterm > 0 && tid < NB*P1*nterm){
      int cell1 = tid / nterm;
      int k = 1 + tid % nterm;
      int b = cell1 / P1, left = cell1 % P1;
      // diag L+1 span (left): lcell=(left,k), rcell=(left+k+1, L-k)
      int lc = b*NCELL + coff(k) + left;
      int rc = b*NCELL + coff(L-k) + left+k+1;
      float v = compat_dot(cU, cH, cC, cS, lc, rc, lane);
      if (lane==0) compatW[(b*NW + left)*NW + k] = v;
    }
    return;
  }

  const int cellid = blk >> 4;
  const int dg = blk & 15;            // dim-group: dims [dg*32, dg*32+32)
  const int b = cellid / P;
  const int left = cellid % P;
  __shared__ float compat_s[32];
  __shared__ float wts_s[32];
  __shared__ float S_s;
  __shared__ float partH[8][32];
  __shared__ float partC[8][32];

  // phase 1: boundary terms inline (k=0 by wave 0, k=L-1 by wave 1);
  // interior terms from the precomputed buffer.
  if (wave == 0){
    int lc = b*NCELL + left;                       // (left,0) leaf
    int rc = b*NCELL + coff(L-1) + left+1;
    float v = compat_dot(cU, cH, cC, cS, lc, rc, lane);
    if (lane==0) compat_s[0] = v;
  } else if (wave == 1 && L >= 2){
    int lc = b*NCELL + coff(L-1) + left;
    int rc = b*NCELL + left+L;                     // (left+L,0) leaf
    float v = compat_dot(cU, cH, cC, cS, lc, rc, lane);
    if (lane==0) compat_s[L-1] = v;
  }
  if (t >= 1 && t <= L-2) compat_s[t] = compatR[(b*NW + left)*NW + t];
  __syncthreads();
  // phase 2: softmax over k (L<=23, serial on thread 0)
  if (t==0){
    float mx = -1e30f;
    for (int k=0;k<L;k++) mx = fmaxf(mx, compat_s[k]);
    float den = 0.f;
    for (int k=0;k<L;k++){ float e = __expf(compat_s[k]-mx); wts_s[k]=e; den+=e; }
    float inv = 1.f/den, S = 0.f;
    for (int k=0;k<L;k++){ wts_s[k]*=inv; S += wts_s[k]*compat_s[k]; }
    S_s = S;
  }
  __syncthreads();
  // phase 3: thread owns 1 dim; t>>5 selects k-residue (8-way split)
  const int dloc = t & 31;
  const int dim = dg*32 + dloc;
  const int kpar = t >> 5;
  float aH = 0.f, aC = 0.f;
  for (int k=kpar; k<L; k+=8){
    float wk = wts_s[k];
    int lc = b*NCELL + coff(k) + left;
    int rc = b*NCELL + coff(L-1-k) + left+k+1;
    const float* PI = cPI + (size_t)lc*H5;
    const float* PS = cPS + (size_t)rc*H5;
    float p0 = PI[dim]     + PS[dim];
    float p1 = PI[H+dim]   + PS[H+dim];
    float p2 = PI[2*H+dim] + PS[2*H+dim];
    float p3 = PI[3*H+dim] + PS[3*H+dim];
    float p4 = PI[4*H+dim] + PS[4*H+dim];
    float lcv = cC[(size_t)lc*H + dim];
    float rcv = cC[(size_t)rc*H + dim];
    float mem = sigm(p1)*lcv + sigm(p2)*rcv + sigm(p0)*ftanh(p3);
    float h = sigm(p4)*ftanh(mem);
    aH += wk*h; aC += wk*mem;
  }
  if (kpar > 0){ partH[kpar][dloc]=aH; partC[kpar][dloc]=aC; }
  __syncthreads();
  if (kpar == 0){
    #pragma unroll
    for (int q=1;q<8;q++){ aH += partH[q][dloc]; aC += partC[q][dloc]; }
    if (L == NW-1){                       // root cell: write output directly
      out[b*H2 + dim]     = aH;
      out[b*H2 + H + dim] = aC;
      return;
    }
    size_t nc = (size_t)(b*NCELL + coff(L) + left);
    cH[nc*H + dim] = aH;
    cC[nc*H + dim] = aC;
    split_store(cHbh,cHbl, nc*H + dim, aH);
    split_store(cCbh,cCbl, nc*H + dim, aC);
    if (t==0 && dg==0) cS[nc] = S_s;
  }
}

extern "C" void kernel_launch(void* const* d_in, const int* in_sizes, int n_in,
                              void* d_out, int out_size, void* d_ws, size_t ws_size,
                              hipStream_t stream){
  const float* seqt = (const float*)d_in[0];
  const float* Wi   = (const float*)d_in[1];
  const float* bi   = (const float*)d_in[2];
  const float* Ws   = (const float*)d_in[3];
  const float* bs   = (const float*)d_in[4];
  const float* Wbil = (const float*)d_in[5];
  float* out = (float*)d_out;

  float* p = (ws_size >= NEED_BYTES && g_buf == nullptr) ? (float*)d_ws : g_buf;
  float* cH  = p; p += (size_t)NB*NCELL*H;
  float* cC  = p; p += (size_t)NB*NCELL*H;
  float* cS  = p; p += (size_t)NB*NCELL;
  float* cPI = p; p += (size_t)NB*NCELL*H5;
  float* cPS = p; p += (size_t)NB*NCELL*H5;
  float* cU  = p; p += (size_t)NB*NCELL*H2;
  float* compatA = p; p += (size_t)NB*NW*NW;
  float* compatB = p; p += (size_t)NB*NW*NW;
  ushort_t* u = (ushort_t*)p;
  ushort_t* WWblob = u; u += (size_t)320*16384;   // 320 x 32KB LDS images
  ushort_t* WBblob = u; u += (size_t)64*32768;    // 64 x 64KB LDS images
  ushort_t* cHbh   = u; u += (size_t)NB*NCELL*H;
  ushort_t* cHbl   = u; u += (size_t)NB*NCELL*H;
  ushort_t* cCbh   = u; u += (size_t)NB*NCELL*H;
  ushort_t* cCbl   = u; u += (size_t)NB*NCELL*H;

  k_init<<<2496, 256, 0, stream>>>(seqt, Wi, Ws, Wbil,
      WWblob, WBblob, cH, cC, cS, cHbh, cHbl, cCbh, cCbl);

  k_proj3<<<384, 512, 0, stream>>>(
      WWblob, WBblob, bi, bs,
      cHbh, cHbl, cCbh, cCbl, cPI, cPS, cU, 0, NW);
  for (int L=1; L<NW; L++){
    int P = NW - L;
    // writer blocks precompute compat interior terms for diagonal L+1
    int P1 = P-1, nterm = L-1;
    int wblk = (P1>0 && nterm>0) ? (NB*P1*nterm + 3)/4 : 0;
    float* bufR = (L&1) ? compatA : compatB;
    float* bufW = (L&1) ? compatB : compatA;
    k_combine3<<<NB*P*16 + wblk, 256, 0, stream>>>(
        cPI, cPS, cU, cH, cC, cS, cHbh, cHbl, cCbh, cCbl,
        bufR, bufW, out, L, P);
    if (L < NW-1)
      k_proj3<<<384, 512, 0, stream>>>(
          WWblob, WBblob, bi, bs,
          cHbh, cHbl, cCbh, cCbl, cPI, cPS, cU, L, P);
  }
}

// Round 8
// 569.400 us; speedup vs baseline: 4.0195x; 1.0149x over previous
//
#include <hip/hip_runtime.h>
#include <math.h>

#define NB 4
#define NW 24
#define H 512
#define H2 1024
#define H5 2560
#define NCELL 300   // n*(n+1)/2 valid cells per batch
#define NEED_BYTES ((size_t)72<<20)

// Private fallback workspace: allocated ONCE at library load (outside
// kernel_launch, so graph capture never sees the hipMalloc).
static float* g_buf = nullptr;
__attribute__((constructor)) static void dio_alloc_ws(){
  (void)hipMalloc((void**)&g_buf, NEED_BYTES);
}

typedef __attribute__((ext_vector_type(8))) short bf16x8;   // 8 bf16 (4 VGPRs)
typedef __attribute__((ext_vector_type(4))) float f32x4;
typedef unsigned short ushort_t;

__device__ __forceinline__ int coff(int l){ return l*NW - (l*(l-1))/2; }
__device__ __forceinline__ float sigm(float x){ return 1.f/(1.f+__expf(-x)); }
__device__ __forceinline__ float ftanh(float x){ return 1.f - 2.f/(__expf(2.f*x)+1.f); }

__device__ __forceinline__ ushort_t f2b(float x){  // fp32 -> bf16 RNE
  unsigned int u = __float_as_uint(x);
  u += 0x7FFF + ((u>>16)&1);
  return (ushort_t)(u>>16);
}
__device__ __forceinline__ float b2f(ushort_t h){
  return __uint_as_float(((unsigned int)h)<<16);
}
// split-bf16: x ~= hi + lo with effective ~2^-17 relative error
__device__ __forceinline__ void split_store(ushort_t* __restrict__ ph,
                                            ushort_t* __restrict__ pl,
                                            size_t idx, float x){
  ushort_t h = f2b(x);
  ph[idx] = h;
  pl[idx] = f2b(x - b2f(h));
}

// async global->LDS copy, 16B per lane (dwordx4). LDS dest = uniform base +
// lane*16 (HW rule, learn_hip m104); global src is per-lane.
__device__ __forceinline__ void gload_lds16(const void* g, void* l){
  __builtin_amdgcn_global_load_lds(
      (const __attribute__((address_space(1))) unsigned int*)g,
      (__attribute__((address_space(3))) unsigned int*)l, 16, 0, 0);
}

// full-wave dot: compat(lc,rc) = U[lc].[H(rc);C(rc)] + S[lc] + S[rc]
__device__ __forceinline__ float compat_dot(const float* __restrict__ cU,
                                            const float* __restrict__ cH,
                                            const float* __restrict__ cC,
                                            const float* __restrict__ cS,
                                            int lc, int rc, int lane){
  const float4* U4  = (const float4*)(cU + (size_t)lc*H2);
  const float4* Hr4 = (const float4*)(cH + (size_t)rc*H);
  const float4* Cr4 = (const float4*)(cC + (size_t)rc*H);
  float p = 0.f;
  #pragma unroll
  for (int it=0; it<2; it++){
    float4 u = U4[lane + 64*it], h = Hr4[lane + 64*it];
    p += u.x*h.x + u.y*h.y + u.z*h.z + u.w*h.w;
  }
  #pragma unroll
  for (int it=0; it<2; it++){
    float4 u = U4[128 + lane + 64*it], c = Cr4[lane + 64*it];
    p += u.x*c.x + u.y*c.y + u.z*c.z + u.w*c.w;
  }
  #pragma unroll
  for (int off=32; off>0; off>>=1) p += __shfl_down(p, off);
  return p + cS[lc] + cS[rc];
}

// ---- merged init: weight blobs (pre-swizzled LDS images), leaves.
__global__ void k_init(const float* __restrict__ seqt,
                       const float* __restrict__ Wi, const float* __restrict__ Ws,
                       const float* __restrict__ Wbil,
                       ushort_t* __restrict__ WWblob, ushort_t* __restrict__ WBblob,
                       float* __restrict__ cH, float* __restrict__ cC, float* __restrict__ cS,
                       ushort_t* __restrict__ cHbh, ushort_t* __restrict__ cHbl,
                       ushort_t* __restrict__ cCbh, ushort_t* __restrict__ cCbl){
  const int blk = blockIdx.x, t = threadIdx.x;
  if (blk < 1280){                        // Wi/Ws -> WWblob (8-elem chunks)
    const int gid = blk*256 + t;          // 327680 chunks total
    const int half = 163840;
    const float* mat = (gid < half) ? Wi : Ws;
    const int cid = (gid < half) ? gid : gid - half;
    const int j = cid >> 6;               // row 0..2559
    const int c0 = (cid & 63) << 3;       // col chunk base
    const int tile = ((gid < half) ? 0 : 160) + (j >> 4);
    const int row = j & 15;
    const float4* s = (const float4*)(mat + (size_t)j*H + c0);
    float4 a = s[0], b4 = s[1];
    float xs[8] = {a.x,a.y,a.z,a.w, b4.x,b4.y,b4.z,b4.w};
    union { ushort_t u[8]; bf16x8 v; } hh, ll;
    #pragma unroll
    for (int i=0;i<8;i++){
      ushort_t h = f2b(xs[i]);
      hh.u[i] = h; ll.u[i] = f2b(xs[i] - b2f(h));
    }
    char* base = (char*)WWblob + (size_t)tile*32768;
    const int off = ((row<<10) + (c0<<1)) ^ ((row&7)<<4);
    *(bf16x8*)(base + off) = hh.v;
    *(bf16x8*)(base + 16384 + off) = ll.v;
  } else if (blk < 2304){                 // Wbil transpose -> WBblob (1024 tiles)
    __shared__ float tile[32][33];
    int tb = blk - 1280;
    int tr = (tb>>5)*32, tc = (tb&31)*32;
    int tx = t & 31, ty = t >> 5;         // 32 x 8
    #pragma unroll
    for (int i=0;i<32;i+=8)
      tile[ty+i][tx] = Wbil[(size_t)(tr+ty+i)*H2 + tc+tx];
    __syncthreads();
    if (t < 128){                         // 32 cols x 4 k-chunks of 8
      const int c = t & 31, r0 = (t >> 5) << 3;
      const int jg = tc + c;              // output row (Wbil column)
      const int k0 = tr + r0;             // output k-chunk base
      union { ushort_t u[8]; bf16x8 v; } hh, ll;
      #pragma unroll
      for (int i=0;i<8;i++){
        float x = tile[r0+i][c];
        ushort_t h = f2b(x);
        hh.u[i] = h; ll.u[i] = f2b(x - b2f(h));
      }
      char* base = (char*)WBblob + (size_t)(jg>>4)*65536;
      const int row = jg & 15;
      const int off = ((row<<11) + (k0<<1)) ^ ((row&7)<<4);
      *(bf16x8*)(base + off) = hh.v;
      *(bf16x8*)(base + 32768 + off) = ll.v;
    }
  } else {                                // leaves (192 blocks)
    int tid = (blk-2304)*256 + t;
    if (tid < NB*NW*H){
      int b = tid/(NW*H); int r = tid%(NW*H); int i = r/H; int d = r%H;
      size_t idx = (size_t)(b*NCELL + i)*H + d;     // coff(0)==0
      float hv = seqt[(size_t)(b*NW+i)*H2 + d];
      float cv = seqt[(size_t)(b*NW+i)*H2 + H + d];
      cH[idx]=hv; cC[idx]=cv;
      split_store(cHbh,cHbl,idx,hv);
      split_store(cCbh,cCbl,idx,cv);
      if (d==0) cS[b*NCELL+i] = 0.f;
    }
  }
}

__device__ __forceinline__ void mfma3(f32x4& acc, bf16x8 ah, bf16x8 al,
                                      bf16x8 bh, bf16x8 bl){
  // split product; lo*lo (~2^-34 rel) dropped
  acc = __builtin_amdgcn_mfma_f32_16x16x32_bf16(ah, bh, acc, 0,0,0);
  acc = __builtin_amdgcn_mfma_f32_16x16x32_bf16(ah, bl, acc, 0,0,0);
  acc = __builtin_amdgcn_mfma_f32_16x16x32_bf16(al, bh, acc, 0,0,0);
}

// ---- MFMA projections of diag d + INTERIOR-GATE precompute for diag d+1.
// Blocks [0,384): proj j-tiles (identical to round 7, bit-exact).
// Blocks [384, 384+ngate): gate blocks — one per (b,left,k-interior) of the
// NEXT diagonal Ln=d+1. They read ONLY diags <= Ln-2 (strictly older than
// anything this dispatch writes -> no sync), compute the exact combine
// mem/h expressions unweighted, store fp32 to gH/gM. Combine then reads 2
// floats instead of 12 per interior (k,dim). fp32 store/reload is exact ->
// bit-exact overall.
__global__ void __launch_bounds__(512)
k_proj4(const ushort_t* __restrict__ WWblob, const ushort_t* __restrict__ WBblob,
        const float* __restrict__ bi, const float* __restrict__ bs,
        const ushort_t* __restrict__ cHbh, const ushort_t* __restrict__ cHbl,
        const ushort_t* __restrict__ cCbh, const ushort_t* __restrict__ cCbl,
        const float* __restrict__ cC,
        float* __restrict__ cPI, float* __restrict__ cPS, float* __restrict__ cU,
        float* __restrict__ gH, float* __restrict__ gM,
        int d, int P)
{
  __shared__ __attribute__((aligned(16))) ushort_t wlds[32768];  // 64 KB
  __shared__ f32x4 red[8][64];                                   // 8 KB
  const int t = threadIdx.x, wv = t>>6, lane = t&63;
  const int jt = blockIdx.x;

  if (jt >= 384){
    // ---- gate block for diag Ln = d+1, interior split k in [1,Ln-2]
    const int Ln = d + 1;
    const int nk = Ln - 2;               // >=1 guaranteed by launcher
    const int Pg = NW - Ln;
    const int gi = jt - 384;             // < NB*Pg*nk
    const int b = gi / (Pg*nk), rr = gi % (Pg*nk);
    const int left = rr / nk;
    const int k = 1 + rr % nk;
    const int lc = b*NCELL + coff(k) + left;
    const int rc = b*NCELL + coff(Ln-1-k) + left+k+1;
    const float* PI = cPI + (size_t)lc*H5;
    const float* PS = cPS + (size_t)rc*H5;
    const int dim = t;                   // 512 threads = 512 dims
    float p0 = PI[dim]     + PS[dim];
    float p1 = PI[H+dim]   + PS[H+dim];
    float p2 = PI[2*H+dim] + PS[2*H+dim];
    float p3 = PI[3*H+dim] + PS[3*H+dim];
    float p4 = PI[4*H+dim] + PS[4*H+dim];
    float lcv = cC[(size_t)lc*H + dim];
    float rcv = cC[(size_t)rc*H + dim];
    float mem = sigm(p1)*lcv + sigm(p2)*rcv + sigm(p0)*ftanh(p3);
    float h = sigm(p4)*ftanh(mem);
    const size_t gidx = ((size_t)(b*NW + left)*NW + k)*H + dim;
    gH[gidx] = h;
    gM[gidx] = mem;
    return;
  }

  const int r = lane & 15;   // A row (m) / B row (j) / D col
  const int q = lane >> 4;   // quad: k = q*8 + i

  int kind, j0;
  if (jt < 160){ kind=0; j0 = jt*16; }
  else if (jt < 320){ kind=1; j0 = (jt-160)*16; }
  else { kind=2; j0 = (jt-320)*16; }

  // ---- stage weights into LDS: linear async copy of the blob image
  {
    const char* blob = (kind < 2)
        ? (const char*)WWblob + (size_t)jt*32768
        : (const char*)WBblob + (size_t)(jt-320)*65536;
    const int nseg = (kind < 2) ? 4 : 8;          // 8KB segments
    for (int i = 0; i < nseg; i++){
      const int lo = i*8192 + wv*1024;
      gload_lds16(blob + lo + lane*16, (char*)wlds + lo);
    }
    asm volatile("s_waitcnt vmcnt(0)" ::: "memory");
  }
  __syncthreads();

  const int Mtot = NB*P, mt = (Mtot+15)>>4;
  const int swz = (r&7)<<4;
  const char* wb = (const char*)wlds;
  const int jo = j0 + r;
  float bias = 0.f;
  if (kind==0) bias = bi[jo] + ((jo>=H && jo<3*H)?1.f:0.f);   // ins_bias on [H,3H)
  else if (kind==1) bias = bs[jo];

  const f32x4 z4 = {0.f,0.f,0.f,0.f};
  const int units = 2*mt;                 // (m-tile, K-half) pairs
  const int rounds = (units + 7) >> 3;
  for (int rd = 0; rd < rounds; rd++){
    const int u = rd*8 + wv;
    const int half = u & 1;               // wv parity (rd*8 even)
    const int mtile = u >> 1;
    f32x4 sA = z4;
    int m0 = 0, nm = 0;
    if (u < units){
      m0 = mtile*16;
      nm = min(16, Mtot - m0);
      const int mg = m0 + (r < nm ? r : 0);
      const size_t arow = (size_t)((mg/P)*NCELL + coff(d) + mg%P)*H;
      f32x4 acc[4];
      #pragma unroll
      for (int wi=0;wi<4;wi++) acc[wi] = z4;
      if (kind < 2){
        #pragma unroll
        for (int wi=0; wi<4; wi++){
          const int w = half*4 + wi;      // chain id 0..7
          #pragma unroll
          for (int s=0;s<2;s++){
            const int ko = w*64 + q*8 + s*32;
            bf16x8 ah = *(const bf16x8*)(cHbh + arow + ko);
            bf16x8 al = *(const bf16x8*)(cHbl + arow + ko);
            const int bo = ((r<<10) + (ko<<1)) ^ swz;
            bf16x8 bh = *(const bf16x8*)(wb + bo);
            bf16x8 bl = *(const bf16x8*)(wb + 16384 + bo);
            mfma3(acc[wi], ah, al, bh, bl);
          }
        }
      } else {
        // U: chains 0-3 -> H chart, 4-7 -> C chart; global k = w*128 + ...
        const ushort_t* ah_ = (half==0 ? cHbh : cCbh) + arow;
        const ushort_t* al_ = (half==0 ? cHbl : cCbl) + arow;
        #pragma unroll
        for (int wi=0; wi<4; wi++){
          const int w = half*4 + wi;
          const int kg0 = w*128, ka0 = kg0 & 511;
          #pragma unroll
          for (int s=0;s<4;s++){
            const int so = s*32 + q*8;
            bf16x8 ah = *(const bf16x8*)(ah_ + ka0 + so);
            bf16x8 al = *(const bf16x8*)(al_ + ka0 + so);
            const int bo = ((r<<11) + ((kg0+so)<<1)) ^ swz;
            bf16x8 bh = *(const bf16x8*)(wb + bo);
            bf16x8 bl = *(const bf16x8*)(wb + 32768 + bo);
            mfma3(acc[wi], ah, al, bh, bl);
          }
        }
      }
      sA = (acc[0]+acc[1]) + (acc[2]+acc[3]);   // half-subtree, fixed order
    }
    red[wv][lane] = sA;
    __syncthreads();
    if (half==0 && u < units){
      f32x4 tot = red[wv][lane] + red[wv|1][lane];   // ((0+1)+(2+3))+((4+5)+(6+7))
      #pragma unroll
      for (int reg=0; reg<4; reg++){
        const int m = q*4 + reg;
        if (m < nm){
          const int mg2 = m0 + m;
          const size_t cell = (size_t)((mg2/P)*NCELL + coff(d) + mg2%P);
          const float v = tot[reg];
          if (kind==0)      cPI[cell*H5 + jo] = v + bias;
          else if (kind==1) cPS[cell*H5 + jo] = v + bias;
          else              cU [cell*H2 + jo] = v;
        }
      }
    }
    __syncthreads();   // red reused next round
  }
}

// ---- combine diagonal L. Interior gates (k in [1,L-2]) come precomputed
// from the preceding proj dispatch (gH/gM); only boundary k=0 / k=L-1 are
// computed inline (they need diag L-1 proj, available since prev dispatch).
// Accumulation order per thread identical to round 2 -> bit-exact.
// grid.x = NB*P*16 phase blocks + ceil(NB*(P-1)*(L-1)/4) writer blocks.
__global__ void __launch_bounds__(256)
k_combine4(const float* __restrict__ cPI, const float* __restrict__ cPS,
           const float* __restrict__ cU,
           float* __restrict__ cH, float* __restrict__ cC, float* __restrict__ cS,
           ushort_t* __restrict__ cHbh, ushort_t* __restrict__ cHbl,
           ushort_t* __restrict__ cCbh, ushort_t* __restrict__ cCbl,
           const float* __restrict__ compatR, float* __restrict__ compatW,
           const float* __restrict__ gH, const float* __restrict__ gM,
           float* __restrict__ out, int L, int P){
  const int t = threadIdx.x;
  const int lane = t & 63;
  const int wave = t >> 6;
  const int nphase = NB*P*16;
  const int blk = blockIdx.x;

  if (blk >= nphase){
    // writer: one wave per (cell of diag L+1, split k in [1,L-1])
    const int P1 = P-1;
    const int nterm = L-1;
    int tid = (blk-nphase)*4 + wave;
    if (P1 > 0 && nterm > 0 && tid < NB*P1*nterm){
      int cell1 = tid / nterm;
      int k = 1 + tid % nterm;
      int b = cell1 / P1, left = cell1 % P1;
      // diag L+1 span (left): lcell=(left,k), rcell=(left+k+1, L-k)
      int lc = b*NCELL + coff(k) + left;
      int rc = b*NCELL + coff(L-k) + left+k+1;
      float v = compat_dot(cU, cH, cC, cS, lc, rc, lane);
      if (lane==0) compatW[(b*NW + left)*NW + k] = v;
    }
    return;
  }

  const int cellid = blk >> 4;
  const int dg = blk & 15;            // dim-group: dims [dg*32, dg*32+32)
  const int b = cellid / P;
  const int left = cellid % P;
  __shared__ float compat_s[32];
  __shared__ float wts_s[32];
  __shared__ float S_s;
  __shared__ float partH[8][32];
  __shared__ float partC[8][32];

  // phase 1: boundary terms inline (k=0 by wave 0, k=L-1 by wave 1);
  // interior terms from the precomputed buffer.
  if (wave == 0){
    int lc = b*NCELL + left;                       // (left,0) leaf
    int rc = b*NCELL + coff(L-1) + left+1;
    float v = compat_dot(cU, cH, cC, cS, lc, rc, lane);
    if (lane==0) compat_s[0] = v;
  } else if (wave == 1 && L >= 2){
    int lc = b*NCELL + coff(L-1) + left;
    int rc = b*NCELL + left+L;                     // (left+L,0) leaf
    float v = compat_dot(cU, cH, cC, cS, lc, rc, lane);
    if (lane==0) compat_s[L-1] = v;
  }
  if (t >= 1 && t <= L-2) compat_s[t] = compatR[(b*NW + left)*NW + t];
  __syncthreads();
  // phase 2: softmax over k (L<=23, serial on thread 0)
  if (t==0){
    float mx = -1e30f;
    for (int k=0;k<L;k++) mx = fmaxf(mx, compat_s[k]);
    float den = 0.f;
    for (int k=0;k<L;k++){ float e = __expf(compat_s[k]-mx); wts_s[k]=e; den+=e; }
    float inv = 1.f/den, S = 0.f;
    for (int k=0;k<L;k++){ wts_s[k]*=inv; S += wts_s[k]*compat_s[k]; }
    S_s = S;
  }
  __syncthreads();
  // phase 3: thread owns 1 dim; t>>5 selects k-residue (8-way split)
  const int dloc = t & 31;
  const int dim = dg*32 + dloc;
  const int kpar = t >> 5;
  float aH = 0.f, aC = 0.f;
  for (int k=kpar; k<L; k+=8){
    float wk = wts_s[k];
    float mem, h;
    if (k == 0 || k == L-1){
      int lc = b*NCELL + coff(k) + left;
      int rc = b*NCELL + coff(L-1-k) + left+k+1;
      const float* PI = cPI + (size_t)lc*H5;
      const float* PS = cPS + (size_t)rc*H5;
      float p0 = PI[dim]     + PS[dim];
      float p1 = PI[H+dim]   + PS[H+dim];
      float p2 = PI[2*H+dim] + PS[2*H+dim];
      float p3 = PI[3*H+dim] + PS[3*H+dim];
      float p4 = PI[4*H+dim] + PS[4*H+dim];
      float lcv = cC[(size_t)lc*H + dim];
      float rcv = cC[(size_t)rc*H + dim];
      mem = sigm(p1)*lcv + sigm(p2)*rcv + sigm(p0)*ftanh(p3);
      h = sigm(p4)*ftanh(mem);
    } else {
      const size_t gidx = ((size_t)(b*NW + left)*NW + k)*H + dim;
      h = gH[gidx];
      mem = gM[gidx];
    }
    aH += wk*h; aC += wk*mem;
  }
  if (kpar > 0){ partH[kpar][dloc]=aH; partC[kpar][dloc]=aC; }
  __syncthreads();
  if (kpar == 0){
    #pragma unroll
    for (int q=1;q<8;q++){ aH += partH[q][dloc]; aC += partC[q][dloc]; }
    if (L == NW-1){                       // root cell: write output directly
      out[b*H2 + dim]     = aH;
      out[b*H2 + H + dim] = aC;
      return;
    }
    size_t nc = (size_t)(b*NCELL + coff(L) + left);
    cH[nc*H + dim] = aH;
    cC[nc*H + dim] = aC;
    split_store(cHbh,cHbl, nc*H + dim, aH);
    split_store(cCbh,cCbl, nc*H + dim, aC);
    if (t==0 && dg==0) cS[nc] = S_s;
  }
}

extern "C" void kernel_launch(void* const* d_in, const int* in_sizes, int n_in,
                              void* d_out, int out_size, void* d_ws, size_t ws_size,
                              hipStream_t stream){
  const float* seqt = (const float*)d_in[0];
  const float* Wi   = (const float*)d_in[1];
  const float* bi   = (const float*)d_in[2];
  const float* Ws   = (const float*)d_in[3];
  const float* bs   = (const float*)d_in[4];
  const float* Wbil = (const float*)d_in[5];
  float* out = (float*)d_out;

  float* p = (ws_size >= NEED_BYTES && g_buf == nullptr) ? (float*)d_ws : g_buf;
  float* cH  = p; p += (size_t)NB*NCELL*H;
  float* cC  = p; p += (size_t)NB*NCELL*H;
  float* cS  = p; p += (size_t)NB*NCELL;
  float* cPI = p; p += (size_t)NB*NCELL*H5;
  float* cPS = p; p += (size_t)NB*NCELL*H5;
  float* cU  = p; p += (size_t)NB*NCELL*H2;
  float* compatA = p; p += (size_t)NB*NW*NW;
  float* compatB = p; p += (size_t)NB*NW*NW;
  float* gH  = p; p += (size_t)NB*NW*NW*H;        // interior gate h (fp32)
  float* gM  = p; p += (size_t)NB*NW*NW*H;        // interior gate mem (fp32)
  ushort_t* u = (ushort_t*)p;
  ushort_t* WWblob = u; u += (size_t)320*16384;   // 320 x 32KB LDS images
  ushort_t* WBblob = u; u += (size_t)64*32768;    // 64 x 64KB LDS images
  ushort_t* cHbh   = u; u += (size_t)NB*NCELL*H;
  ushort_t* cHbl   = u; u += (size_t)NB*NCELL*H;
  ushort_t* cCbh   = u; u += (size_t)NB*NCELL*H;
  ushort_t* cCbl   = u; u += (size_t)NB*NCELL*H;

  k_init<<<2496, 256, 0, stream>>>(seqt, Wi, Ws, Wbil,
      WWblob, WBblob, cH, cC, cS, cHbh, cHbl, cCbh, cCbl);

  // proj(0): diag 0; next diagonal Ln=1 has no interior gates
  k_proj4<<<384, 512, 0, stream>>>(
      WWblob, WBblob, bi, bs,
      cHbh, cHbl, cCbh, cCbl, cC, cPI, cPS, cU, gH, gM, 0, NW);
  for (int L=1; L<NW; L++){
    int P = NW - L;
    // writer blocks precompute compat interior terms for diagonal L+1
    int P1 = P-1, nterm = L-1;
    int wblk = (P1>0 && nterm>0) ? (NB*P1*nterm + 3)/4 : 0;
    float* bufR = (L&1) ? compatA : compatB;
    float* bufW = (L&1) ? compatB : compatA;
    k_combine4<<<NB*P*16 + wblk, 256, 0, stream>>>(
        cPI, cPS, cU, cH, cC, cS, cHbh, cHbl, cCbh, cCbl,
        bufR, bufW, gH, gM, out, L, P);
    if (L < NW-1){
      // proj(L): diag L; also precompute interior gates for diag Ln=L+1
      int Ln = L + 1;
      int ngate = (Ln >= 3) ? NB*(NW-Ln)*(Ln-2) : 0;
      k_proj4<<<384 + ngate, 512, 0, stream>>>(
          WWblob, WBblob, bi, bs,
          cHbh, cHbl, cCbh, cCbl, cC, cPI, cPS, cU, gH, gM, L, P);
    }
  }
}